// Round 4
// baseline (300.911 us; speedup 1.0000x reference)
//
#include <hip/hip_runtime.h>

// KNRM round 4: fully per-wave, LDS-free, barrier-free.
// Each wave owns one 16q x 32d tile of one batch: loads fp32 embedding rows
// directly from the table as MFMA fragments (dwordx4), converts to bf16
// in-register (RNE), accumulates sum-of-squares of the ROUNDED values for the
// reciprocal norms (=> exact-token-match cosine == 1, required by kernel0
// sigma=1e-4), MFMAs, applies the 11 Gaussians on accumulator registers,
// shuffle-reduces over the 16 doc lanes, and stores contention-free partials
// pkq_part[b][chunk][32][11] (every slot written by exactly one wave -> no
// memset, no atomics). Tiny epilogue sums the 16 chunks, log/mask/dot -> out.

#define B      256
#define BQ     32
#define BD     512
#define EDIM   300
#define NK     11
#define NCHUNK 16            // 512 / 32 doc-cols per wave

typedef float floatx4 __attribute__((ext_vector_type(4)));
typedef short shortx8 __attribute__((ext_vector_type(8)));

__device__ __forceinline__ unsigned short f2bf(float f) {
    unsigned int u = __float_as_uint(f);
    return (unsigned short)((u + 0x7fffu + ((u >> 16) & 1u)) >> 16);  // RNE
}
__device__ __forceinline__ float bf2f(unsigned short h) {
    return __uint_as_float(((unsigned int)h) << 16);
}

// 8 consecutive in-bounds fp32 -> bf16 frag; ss += sum of squares of rounded.
__device__ __forceinline__ shortx8 cvt8(const float* __restrict__ p, float& ss) {
    float4 v0 = *(const float4*)p;
    float4 v1 = *(const float4*)(p + 4);
    float f[8] = {v0.x, v0.y, v0.z, v0.w, v1.x, v1.y, v1.z, v1.w};
    union { shortx8 v; unsigned short u[8]; } r;
    #pragma unroll
    for (int j = 0; j < 8; ++j) {
        unsigned short h = f2bf(f[j]);
        r.u[j] = h;
        float g = bf2f(h);
        ss += g * g;
    }
    return r.v;
}

// tail frag: cols c..c+7, zero where col >= EDIM (address-clamped, no OOB).
__device__ __forceinline__ shortx8 cvt8_tail(const float* __restrict__ row, int c, float& ss) {
    union { shortx8 v; unsigned short u[8]; } r;
    #pragma unroll
    for (int j = 0; j < 8; ++j) {
        int col = c + j;
        int cc = (col < EDIM) ? col : 0;
        float f = row[cc];
        f = (col < EDIM) ? f : 0.f;
        unsigned short h = f2bf(f);
        r.u[j] = h;
        float g = bf2f(h);
        ss += g * g;
    }
    return r.v;
}

__global__ __launch_bounds__(256)
void knrm_wave(const int* __restrict__ qtok, const int* __restrict__ dtok,
               const float* __restrict__ emb,
               const float* __restrict__ mu, const float* __restrict__ sigma,
               float* __restrict__ pkq_part)
{
    const int tid   = threadIdx.x;
    const int lane  = tid & 63;
    const int wv    = tid >> 6;
    const int b     = blockIdx.x >> 3;
    const int g     = blockIdx.x & 7;
    const int chunk = g * 2 + (wv & 1);      // 0..15
    const int mbase = (wv >> 1) * 16;        // 0 or 16
    const int nbase = chunk * 32;
    const int l16   = lane & 15;
    const int quad  = lane >> 4;

    float mur[NK], cfr[NK];
    #pragma unroll
    for (int k = 0; k < NK; ++k) {
        float s = sigma[k];
        mur[k] = mu[k];
        cfr[k] = -0.5f / (s * s);
    }

    const int tq  = qtok[b * BQ + mbase + l16];
    const int td0 = dtok[b * BD + nbase + l16];
    const int td1 = dtok[b * BD + nbase + 16 + l16];
    const float* arow  = emb + (size_t)tq  * EDIM;
    const float* b0row = emb + (size_t)td0 * EDIM;
    const float* b1row = emb + (size_t)td1 * EDIM;

    float ssa = 0.f, ssb0 = 0.f, ssb1 = 0.f;
    floatx4 acc0 = {0.f, 0.f, 0.f, 0.f};
    floatx4 acc1 = {0.f, 0.f, 0.f, 0.f};
    const int cb = quad * 8;

    #pragma unroll
    for (int ks = 0; ks < 9; ++ks) {         // cols 0..287: all frags in-bounds
        int c = cb + ks * 32;
        shortx8 a  = cvt8(arow  + c, ssa);
        shortx8 b0 = cvt8(b0row + c, ssb0);
        shortx8 b1 = cvt8(b1row + c, ssb1);
        acc0 = __builtin_amdgcn_mfma_f32_16x16x32_bf16(a, b0, acc0, 0, 0, 0);
        acc1 = __builtin_amdgcn_mfma_f32_16x16x32_bf16(a, b1, acc1, 0, 0, 0);
    }
    {                                        // tail: cols 288..319, zero >= 300
        int c = 288 + cb;
        shortx8 a  = cvt8_tail(arow,  c, ssa);
        shortx8 b0 = cvt8_tail(b0row, c, ssb0);
        shortx8 b1 = cvt8_tail(b1row, c, ssb1);
        acc0 = __builtin_amdgcn_mfma_f32_16x16x32_bf16(a, b0, acc0, 0, 0, 0);
        acc1 = __builtin_amdgcn_mfma_f32_16x16x32_bf16(a, b1, acc1, 0, 0, 0);
    }

    // full-row sum of squares: reduce over the 4 quads (lanes sharing l16)
    ssa  += __shfl_xor(ssa, 16);  ssa  += __shfl_xor(ssa, 32);
    ssb0 += __shfl_xor(ssb0, 16); ssb0 += __shfl_xor(ssb0, 32);
    ssb1 += __shfl_xor(ssb1, 16); ssb1 += __shfl_xor(ssb1, 32);
    float rq  = 1.f / (sqrtf(ssa)  + 1e-13f);   // q-row (mbase + l16)
    float rd0 = 1.f / (sqrtf(ssb0) + 1e-13f);   // d-col (nbase + l16)
    float rd1 = 1.f / (sqrtf(ssb1) + 1e-13f);   // d-col (nbase + 16 + l16)
    float dm0 = (td0 > 0) ? 1.f : 0.f;
    float dm1 = (td1 > 0) ? 1.f : 0.f;

    // accumulator rows are quad*4+r -> fetch their rq from lane quad*4+r
    float rqv[4];
    #pragma unroll
    for (int r = 0; r < 4; ++r) rqv[r] = __shfl(rq, quad * 4 + r);

    float* dst = pkq_part + (size_t)(b * NCHUNK + chunk) * (BQ * NK);
    #pragma unroll
    for (int r = 0; r < 4; ++r) {
        float c0 = acc0[r] * rqv[r] * rd0;
        float c1 = acc1[r] * rqv[r] * rd1;
        int q = mbase + quad * 4 + r;
        #pragma unroll
        for (int k = 0; k < NK; ++k) {
            float d0 = c0 - mur[k];
            float d1 = c1 - mur[k];
            float v = dm0 * __expf(cfr[k] * d0 * d0)
                    + dm1 * __expf(cfr[k] * d1 * d1);
            v += __shfl_xor(v, 1);
            v += __shfl_xor(v, 2);
            v += __shfl_xor(v, 4);
            v += __shfl_xor(v, 8);
            if (l16 == 0) dst[q * NK + k] = v;   // unique writer per slot
        }
    }
}

__global__ __launch_bounds__(64)
void knrm_epi(const int* __restrict__ qtok, const float* __restrict__ dw,
              const float* __restrict__ db, const float* __restrict__ pkq_part,
              float* __restrict__ out)
{
    int b = blockIdx.x, lane = threadIdx.x;
    float sq = 0.f;
    if (lane < BQ) {
        int tok = qtok[b * BQ + lane];
        if (tok > 0) {
            #pragma unroll
            for (int k = 0; k < NK; ++k) {
                float s = 0.f;
                #pragma unroll
                for (int c = 0; c < NCHUNK; ++c)
                    s += pkq_part[((size_t)(b * NCHUNK + c) * BQ + lane) * NK + k];
                sq += __logf(fmaxf(s, 1e-10f)) * 0.01f * dw[k];
            }
        }
    }
    sq += __shfl_xor(sq, 1);
    sq += __shfl_xor(sq, 2);
    sq += __shfl_xor(sq, 4);
    sq += __shfl_xor(sq, 8);
    sq += __shfl_xor(sq, 16);
    sq += __shfl_xor(sq, 32);
    if (lane == 0) out[b] = sq + db[0];
}

extern "C" void kernel_launch(void* const* d_in, const int* in_sizes, int n_in,
                              void* d_out, int out_size, void* d_ws, size_t ws_size,
                              hipStream_t stream)
{
    const int*   qtok  = (const int*)d_in[0];
    const int*   dtok  = (const int*)d_in[1];
    const float* emb   = (const float*)d_in[2];
    const float* dw    = (const float*)d_in[3];
    const float* dbias = (const float*)d_in[4];
    const float* mu    = (const float*)d_in[5];
    const float* sg    = (const float*)d_in[6];
    float* out      = (float*)d_out;
    float* pkq_part = (float*)d_ws;    // B*NCHUNK*BQ*NK floats = 7.2 MB

    knrm_wave<<<B * 8, 256, 0, stream>>>(qtok, dtok, emb, mu, sg, pkq_part);
    knrm_epi<<<B, 64, 0, stream>>>(qtok, dw, dbias, pkq_part, out);
}

// Round 5
// 250.820 us; speedup vs baseline: 1.1997x; 1.1997x over previous
//
#include <hip/hip_runtime.h>

// KNRM round 5: three-phase, high-concurrency main kernel.
//  Phase 1 (knrm_norm): stream fp32 table -> bf16 rows padded to 320 cols
//    (zeros in [300,320)) + reciprocal norms FROM the rounded values
//    (exact-token-match => cosine == 1, required by kernel0 sigma=1e-4).
//  Phase 2 (knrm_main3): grid = B(256) x 8, 256 thr. Per block: stage one
//    64-row d-tile to LDS (stride 324 halves -> conflict-free b128 reads);
//    q A-fragments load DIRECTLY to registers (no q LDS, no reuse exists);
//    one barrier; MFMA 16x16x32; Gaussians on acc regs; shuffle-reduce over
//    doc lanes; contention-free partial store pkq_part[b][16 chunks][32][11].
//    LDS = 41.5 KB -> 3 blocks/CU (12 waves) vs round-3's 2 (8 waves).
//  Phase 3 (knrm_epi): sum 16 chunk partials, log/mask/dot -> out[B].

#define B      256
#define BQ     32
#define BD     512
#define EDIM   300
#define KPAD   320
#define NK     11
#define DTILE  64
#define NCHUNK 16
#define DSTR   324   // d_buf row stride in halfwords: 162 words == 2 mod 32

typedef float floatx4 __attribute__((ext_vector_type(4)));
typedef short shortx8 __attribute__((ext_vector_type(8)));

__device__ __forceinline__ unsigned short f2bf(float f) {
    unsigned int u = __float_as_uint(f);
    return (unsigned short)((u + 0x7fffu + ((u >> 16) & 1u)) >> 16);  // RNE
}
__device__ __forceinline__ float bf2f(unsigned short h) {
    return __uint_as_float(((unsigned int)h) << 16);
}

// ---------------- Phase 1: normalize / convert table ----------------
__global__ __launch_bounds__(256)
void knrm_norm(const float* __restrict__ emb, unsigned short* __restrict__ ebf,
               float* __restrict__ rnorm, int V)
{
    int r    = blockIdx.x * 16 + (threadIdx.x >> 4);
    int part = threadIdx.x & 15;
    if (r >= V) return;
    const float4* src = (const float4*)(emb + (size_t)r * EDIM);
    uint2*        dst = (uint2*)(ebf + (size_t)r * KPAD);
    float ss = 0.f;
    #pragma unroll
    for (int i = 0; i < 5; ++i) {
        int c = part + i * 16;            // 80 uint2 = 640 B row
        uint2 p = {0u, 0u};
        if (c < EDIM / 4) {
            float4 v = src[c];
            unsigned short h0 = f2bf(v.x), h1 = f2bf(v.y), h2 = f2bf(v.z), h3 = f2bf(v.w);
            p.x = (unsigned int)h0 | ((unsigned int)h1 << 16);
            p.y = (unsigned int)h2 | ((unsigned int)h3 << 16);
            float f0 = bf2f(h0), f1 = bf2f(h1), f2 = bf2f(h2), f3 = bf2f(h3);
            ss += f0 * f0 + f1 * f1 + f2 * f2 + f3 * f3;
        }
        dst[c] = p;                       // pad region gets zeros
    }
    ss += __shfl_xor(ss, 1);
    ss += __shfl_xor(ss, 2);
    ss += __shfl_xor(ss, 4);
    ss += __shfl_xor(ss, 8);
    if (part == 0) rnorm[r] = 1.f / (sqrtf(ss) + 1e-13f);
}

// ---------------- Phase 2: gather + MFMA + Gaussians ----------------
__global__ __launch_bounds__(256)
void knrm_main3(const int* __restrict__ qtok, const int* __restrict__ dtok,
                const unsigned short* __restrict__ ebf, const float* __restrict__ rnorm,
                const float* __restrict__ mu, const float* __restrict__ sigma,
                float* __restrict__ pkq_part)
{
    __shared__ unsigned short d_buf[DTILE * DSTR];   // 41472 B

    const int tid   = threadIdx.x;
    const int lane  = tid & 63;
    const int wv    = tid >> 6;
    const int b     = blockIdx.x >> 3;
    const int g     = blockIdx.x & 7;
    const int l16   = lane & 15;
    const int quad  = lane >> 4;
    const int mbase = (wv & 1) * 16;         // q slab: 0 or 16
    const int sub   = wv >> 1;               // which 32-doc half of the tile
    const int nbase = sub * 32;
    const int chunk = g * 2 + sub;           // 0..15

    // per-lane tokens + norms + masks (scattered dword loads, L2/L3-served)
    const int tq  = qtok[b * BQ + mbase + l16];
    const int td0 = dtok[b * BD + g * DTILE + nbase + l16];
    const int td1 = dtok[b * BD + g * DTILE + nbase + 16 + l16];
    float rq  = rnorm[tq];
    float rd0 = rnorm[td0], dm0 = (td0 > 0) ? 1.f : 0.f;
    float rd1 = rnorm[td1], dm1 = (td1 > 0) ? 1.f : 0.f;

    // A-fragments direct from bf16 table: lane holds A[m=l16][k=quad*8+ks*32+j].
    // 4 quads of one row hit the same 64-B line -> line-coalesced.
    const uint4* asrc = (const uint4*)(ebf + (size_t)tq * KPAD);
    shortx8 afrag[10];
    #pragma unroll
    for (int ks = 0; ks < 10; ++ks)
        afrag[ks] = *(const shortx8*)&asrc[quad + ks * 4];

    float mur[NK], cfr[NK];
    #pragma unroll
    for (int k = 0; k < NK; ++k) {
        float s = sigma[k];
        mur[k] = mu[k];
        cfr[k] = -0.5f / (s * s);
    }

    // stage d tile: 4 threads/row x 10 dwordx4 (coalesced; cols 300..319 are
    // pre-zeroed in ebf, so no pad init needed)
    {
        int row = tid >> 2, part = tid & 3;
        int tok = dtok[b * BD + g * DTILE + row];
        const uint4* src = (const uint4*)(ebf + (size_t)tok * KPAD);
        #pragma unroll
        for (int i = 0; i < 10; ++i) {
            int c = part + i * 4;
            *(uint4*)&d_buf[row * DSTR + c * 8] = src[c];
        }
    }
    __syncthreads();

    const unsigned short* b0ptr = &d_buf[(nbase + l16) * DSTR + quad * 8];
    const unsigned short* b1ptr = b0ptr + 16 * DSTR;

    floatx4 acc0 = {0.f, 0.f, 0.f, 0.f};
    floatx4 acc1 = {0.f, 0.f, 0.f, 0.f};
    #pragma unroll
    for (int ks = 0; ks < 10; ++ks) {
        shortx8 b0 = *(const shortx8*)(b0ptr + ks * 32);
        shortx8 b1 = *(const shortx8*)(b1ptr + ks * 32);
        acc0 = __builtin_amdgcn_mfma_f32_16x16x32_bf16(afrag[ks], b0, acc0, 0, 0, 0);
        acc1 = __builtin_amdgcn_mfma_f32_16x16x32_bf16(afrag[ks], b1, acc1, 0, 0, 0);
    }

    // acc element r of this lane = S[q = mbase+quad*4+r][d = nbase(+16)+l16]
    float rqv[4];
    #pragma unroll
    for (int r = 0; r < 4; ++r) rqv[r] = __shfl(rq, quad * 4 + r);

    float* dst = pkq_part + (size_t)(b * NCHUNK + chunk) * (BQ * NK);
    #pragma unroll
    for (int r = 0; r < 4; ++r) {
        float c0 = acc0[r] * rqv[r] * rd0;
        float c1 = acc1[r] * rqv[r] * rd1;
        int q = mbase + quad * 4 + r;
        #pragma unroll
        for (int k = 0; k < NK; ++k) {
            float d0 = c0 - mur[k];
            float d1 = c1 - mur[k];
            float v = dm0 * __expf(cfr[k] * d0 * d0)
                    + dm1 * __expf(cfr[k] * d1 * d1);
            v += __shfl_xor(v, 1);
            v += __shfl_xor(v, 2);
            v += __shfl_xor(v, 4);
            v += __shfl_xor(v, 8);
            if (l16 == 0) dst[q * NK + k] = v;   // unique writer per slot
        }
    }
}

// ---------------- Phase 3: epilogue ----------------
__global__ __launch_bounds__(64)
void knrm_epi(const int* __restrict__ qtok, const float* __restrict__ dw,
              const float* __restrict__ db, const float* __restrict__ pkq_part,
              float* __restrict__ out)
{
    int b = blockIdx.x, lane = threadIdx.x;
    float sq = 0.f;
    if (lane < BQ) {
        int tok = qtok[b * BQ + lane];
        if (tok > 0) {
            #pragma unroll
            for (int k = 0; k < NK; ++k) {
                float s = 0.f;
                #pragma unroll
                for (int c = 0; c < NCHUNK; ++c)
                    s += pkq_part[((size_t)(b * NCHUNK + c) * BQ + lane) * NK + k];
                sq += __logf(fmaxf(s, 1e-10f)) * 0.01f * dw[k];
            }
        }
    }
    sq += __shfl_xor(sq, 1);
    sq += __shfl_xor(sq, 2);
    sq += __shfl_xor(sq, 4);
    sq += __shfl_xor(sq, 8);
    sq += __shfl_xor(sq, 16);
    sq += __shfl_xor(sq, 32);
    if (lane == 0) out[b] = sq + db[0];
}

extern "C" void kernel_launch(void* const* d_in, const int* in_sizes, int n_in,
                              void* d_out, int out_size, void* d_ws, size_t ws_size,
                              hipStream_t stream)
{
    const int*   qtok  = (const int*)d_in[0];
    const int*   dtok  = (const int*)d_in[1];
    const float* emb   = (const float*)d_in[2];
    const float* dw    = (const float*)d_in[3];
    const float* dbias = (const float*)d_in[4];
    const float* mu    = (const float*)d_in[5];
    const float* sg    = (const float*)d_in[6];
    float* out = (float*)d_out;

    const int V = in_sizes[2] / EDIM;   // 100000
    const size_t ebf_bytes = (size_t)V * KPAD * 2;   // 64 MB
    const size_t rn_bytes  = (size_t)V * 4;          // 0.4 MB

    unsigned short* ebf = (unsigned short*)d_ws;
    float* rnorm        = (float*)((char*)d_ws + ebf_bytes);
    float* pkq_part     = (float*)((char*)d_ws + ebf_bytes + rn_bytes);  // 5.8 MB

    knrm_norm<<<(V + 15) / 16, 256, 0, stream>>>(emb, ebf, rnorm, V);
    knrm_main3<<<B * 8, 256, 0, stream>>>(qtok, dtok, ebf, rnorm, mu, sg, pkq_part);
    knrm_epi<<<B, 64, 0, stream>>>(qtok, dw, dbias, pkq_part, out);
}

// Round 6
// 247.250 us; speedup vs baseline: 1.2170x; 1.0144x over previous
//
#include <hip/hip_runtime.h>

// KNRM round 6: attack the scattered-gather plateau (~3 TB/s effective).
//  Phase 1 (knrm_norm): fp32 table -> bf16 rows padded to 320 cols + rnorm
//    computed FROM the rounded values (exact-match cosine == 1, kernel0
//    sigma=1e-4 requires this).
//  Phase 2 (knrm_main4): grid = 4096 = 16 chunks x 256 batches with
//    b = blockIdx & 255 so all 16 blocks of a batch land on the SAME XCD
//    (round-robin dispatch) -> the x16 redundant q-row reads become L2 hits.
//    32q x 32d tile per block, d-tile (21 KB) in LDS, q A-frags direct to
//    registers. ~5 blocks/CU resident (vs 3 in R5) for more gather
//    concurrency. Per-wave 16x16 acc, Gaussians on acc regs, shuffle-reduce,
//    unique-writer partial stores pkq_part[b][32][32][11] (no memset).
//  Phase 3 (knrm_epi): sum 32 partials, log/mask/dot -> out[B].

#define B      256
#define BQ     32
#define BD     512
#define EDIM   300
#define KPAD   320
#define NK     11
#define DTILE  32
#define NSEMI  32            // 512 / 16 doc-cols per wave-column
#define DSTR   328           // halfwords: 656 B rows, 16B-aligned, 2-way banks (free)

typedef float floatx4 __attribute__((ext_vector_type(4)));
typedef short shortx8 __attribute__((ext_vector_type(8)));

__device__ __forceinline__ unsigned short f2bf(float f) {
    unsigned int u = __float_as_uint(f);
    return (unsigned short)((u + 0x7fffu + ((u >> 16) & 1u)) >> 16);  // RNE
}
__device__ __forceinline__ float bf2f(unsigned short h) {
    return __uint_as_float(((unsigned int)h) << 16);
}

// ---------------- Phase 1: normalize / convert table ----------------
__global__ __launch_bounds__(256)
void knrm_norm(const float* __restrict__ emb, unsigned short* __restrict__ ebf,
               float* __restrict__ rnorm, int V)
{
    int r    = blockIdx.x * 16 + (threadIdx.x >> 4);
    int part = threadIdx.x & 15;
    if (r >= V) return;
    const float4* src = (const float4*)(emb + (size_t)r * EDIM);
    uint2*        dst = (uint2*)(ebf + (size_t)r * KPAD);
    float ss = 0.f;
    #pragma unroll
    for (int i = 0; i < 5; ++i) {
        int c = part + i * 16;            // 80 uint2 = 640 B row
        uint2 p = {0u, 0u};
        if (c < EDIM / 4) {
            float4 v = src[c];
            unsigned short h0 = f2bf(v.x), h1 = f2bf(v.y), h2 = f2bf(v.z), h3 = f2bf(v.w);
            p.x = (unsigned int)h0 | ((unsigned int)h1 << 16);
            p.y = (unsigned int)h2 | ((unsigned int)h3 << 16);
            float f0 = bf2f(h0), f1 = bf2f(h1), f2 = bf2f(h2), f3 = bf2f(h3);
            ss += f0 * f0 + f1 * f1 + f2 * f2 + f3 * f3;
        }
        dst[c] = p;                       // pad region [300,320) gets zeros
    }
    ss += __shfl_xor(ss, 1);
    ss += __shfl_xor(ss, 2);
    ss += __shfl_xor(ss, 4);
    ss += __shfl_xor(ss, 8);
    if (part == 0) rnorm[r] = 1.f / (sqrtf(ss) + 1e-13f);
}

// ---------------- Phase 2: gather + MFMA + Gaussians ----------------
__global__ __launch_bounds__(256, 5)
void knrm_main4(const int* __restrict__ qtok, const int* __restrict__ dtok,
                const unsigned short* __restrict__ ebf, const float* __restrict__ rnorm,
                const float* __restrict__ mu, const float* __restrict__ sigma,
                float* __restrict__ pkq_part)
{
    __shared__ unsigned short d_buf[DTILE * DSTR];   // 20992 B

    const int tid   = threadIdx.x;
    const int lane  = tid & 63;
    const int wv    = tid >> 6;
    const int b     = blockIdx.x & 255;      // XCD swizzle: batch -> XCD b%8
    const int chunk = blockIdx.x >> 8;       // 0..15, 32 doc cols each
    const int l16   = lane & 15;
    const int quad  = lane >> 4;
    const int mbase = (wv & 1) * 16;         // q slab: 0 or 16
    const int nbase = (wv >> 1) * 16;        // d half of the 32-col tile
    const int dbase = chunk * DTILE;

    // tokens + norms + masks
    const int tq = qtok[b * BQ + mbase + l16];
    const int td = dtok[b * BD + dbase + nbase + l16];
    float rq = rnorm[tq];
    float rd = rnorm[td];
    float dm = (td > 0) ? 1.f : 0.f;

    // A-fragments direct from bf16 table: lane holds A[m=l16][k=quad*8+32ks+j]
    const uint4* asrc = (const uint4*)(ebf + (size_t)tq * KPAD);
    shortx8 afrag[10];
    #pragma unroll
    for (int ks = 0; ks < 10; ++ks)
        afrag[ks] = *(const shortx8*)&asrc[quad + ks * 4];

    float mur[NK], cfr[NK];
    #pragma unroll
    for (int k = 0; k < NK; ++k) {
        float s = sigma[k];
        mur[k] = mu[k];
        cfr[k] = -0.5f / (s * s);
    }

    // stage d tile: 8 threads/row x 5 dwordx4 (rows pre-zero-padded in ebf)
    {
        int row = tid >> 3, part = tid & 7;
        int tok = dtok[b * BD + dbase + row];
        const uint4* src = (const uint4*)(ebf + (size_t)tok * KPAD);
        #pragma unroll
        for (int i = 0; i < 5; ++i) {
            int c = part + i * 8;
            *(uint4*)&d_buf[row * DSTR + c * 8] = src[c];
        }
    }
    __syncthreads();

    const unsigned short* bptr = &d_buf[(nbase + l16) * DSTR + quad * 8];
    floatx4 acc = {0.f, 0.f, 0.f, 0.f};
    #pragma unroll
    for (int ks = 0; ks < 10; ++ks) {
        shortx8 bf = *(const shortx8*)(bptr + ks * 32);
        acc = __builtin_amdgcn_mfma_f32_16x16x32_bf16(afrag[ks], bf, acc, 0, 0, 0);
    }

    // acc element r of this lane = S[q = mbase+quad*4+r][d = dbase+nbase+l16]
    float rqv[4];
    #pragma unroll
    for (int r = 0; r < 4; ++r) rqv[r] = __shfl(rq, quad * 4 + r);

    const int semi = chunk * 2 + (nbase >> 4);            // 0..31
    float* dst = pkq_part + (size_t)(b * NSEMI + semi) * (BQ * NK);
    #pragma unroll
    for (int r = 0; r < 4; ++r) {
        float c0 = acc[r] * rqv[r] * rd;
        int q = mbase + quad * 4 + r;
        #pragma unroll
        for (int k = 0; k < NK; ++k) {
            float d0 = c0 - mur[k];
            float v = dm * __expf(cfr[k] * d0 * d0);
            v += __shfl_xor(v, 1);
            v += __shfl_xor(v, 2);
            v += __shfl_xor(v, 4);
            v += __shfl_xor(v, 8);
            if (l16 == 0) dst[q * NK + k] = v;   // unique writer per slot
        }
    }
}

// ---------------- Phase 3: epilogue ----------------
__global__ __launch_bounds__(64)
void knrm_epi(const int* __restrict__ qtok, const float* __restrict__ dw,
              const float* __restrict__ db, const float* __restrict__ pkq_part,
              float* __restrict__ out)
{
    int b = blockIdx.x, lane = threadIdx.x;
    float sq = 0.f;
    if (lane < BQ) {
        int tok = qtok[b * BQ + lane];
        if (tok > 0) {
            #pragma unroll
            for (int k = 0; k < NK; ++k) {
                float s = 0.f;
                #pragma unroll
                for (int c = 0; c < NSEMI; ++c)
                    s += pkq_part[((size_t)(b * NSEMI + c) * BQ + lane) * NK + k];
                sq += __logf(fmaxf(s, 1e-10f)) * 0.01f * dw[k];
            }
        }
    }
    sq += __shfl_xor(sq, 1);
    sq += __shfl_xor(sq, 2);
    sq += __shfl_xor(sq, 4);
    sq += __shfl_xor(sq, 8);
    sq += __shfl_xor(sq, 16);
    sq += __shfl_xor(sq, 32);
    if (lane == 0) out[b] = sq + db[0];
}

extern "C" void kernel_launch(void* const* d_in, const int* in_sizes, int n_in,
                              void* d_out, int out_size, void* d_ws, size_t ws_size,
                              hipStream_t stream)
{
    const int*   qtok  = (const int*)d_in[0];
    const int*   dtok  = (const int*)d_in[1];
    const float* emb   = (const float*)d_in[2];
    const float* dw    = (const float*)d_in[3];
    const float* dbias = (const float*)d_in[4];
    const float* mu    = (const float*)d_in[5];
    const float* sg    = (const float*)d_in[6];
    float* out = (float*)d_out;

    const int V = in_sizes[2] / EDIM;   // 100000
    const size_t ebf_bytes = (size_t)V * KPAD * 2;   // 64 MB
    const size_t rn_bytes  = (size_t)V * 4;          // 0.4 MB

    unsigned short* ebf = (unsigned short*)d_ws;
    float* rnorm        = (float*)((char*)d_ws + ebf_bytes);
    float* pkq_part     = (float*)((char*)d_ws + ebf_bytes + rn_bytes);  // 11.5 MB

    knrm_norm<<<(V + 15) / 16, 256, 0, stream>>>(emb, ebf, rnorm, V);
    knrm_main4<<<B * 16, 256, 0, stream>>>(qtok, dtok, ebf, rnorm, mu, sg, pkq_part);
    knrm_epi<<<B, 64, 0, stream>>>(qtok, dw, dbias, pkq_part, out);
}